// Round 6
// baseline (284.285 us; speedup 1.0000x reference)
//
#include <hip/hip_runtime.h>
#include <hip/hip_cooperative_groups.h>
#include <math.h>

namespace cg = cooperative_groups;

#define Ed 300
#define Sd 64
#define Td 64

__device__ __forceinline__ float sigm(float x) { return 1.0f / (1.0f + expf(-x)); }

// ws layout (floats)
#define OFF_P0A   0          // pre0 part0: 1024*768 = 786432
#define OFF_P0B   786432     // pre0 part1 (includes bias)
#define OFF_P1A   1572864    // preact1 part0: 512*1280 = 655360
#define OFF_P1B   2228224    // preact1 part1 (includes bias)
#define OFF_SOUT  2883584    // 64*256 = 16384
#define OFF_LP    2899968    // 32*8*3 = 768

struct Params {
    const int *sent1, *ops1, *oopl1, *sent2, *ops2, *oopl2;
    const float *glove, *unk, *Wm, *Um, *bv, *eu, *W1, *b1, *W2, *b2;
    float *p0a, *p0b, *p1a, *p1b, *s_out, *lp, *outp;
};

// ---------------------------------------------------------------------------
// Single cooperative kernel, 384 blocks x 256 thr, phases separated by
// grid.sync().  LDS: 34816 B buffer + 256 B tokens -> 2 blocks/CU co-resident.
// ---------------------------------------------------------------------------
__global__ __launch_bounds__(256, 2) void k_fused(Params P)
{
    __shared__ __align__(16) float smem[8704];
    __shared__ int stok[64];
    const int tid = threadIdx.x;
    const int blk = blockIdx.x;
    cg::grid_group grid = cg::this_grid();

    const int tx = tid & 15;       // col group (x4)
    const int ty = tid >> 4;       // row group (x4)

    // ================= P1: pre0[1024][768] = gather(emb) @ Wsel^T ==========
    // 64x64 tiles, k-major LDS, 4x4 register tile, split-K: kc0 k<180, kc1 rest.
    {
        const int kc = blk >= 192;
        const int t = kc ? blk - 192 : blk;
        const int rb = t / 12;
        const int cb = t - rb * 12;
        float* Asw = smem;          // [60][68] k-major
        float* Bsw = smem + 4096;   // [60][68]

        if (tid < 64) {
            const int slot = rb * 64 + tid;          // 0..1023
            const int sp = slot >> 9;
            const int b = (slot >> 4) & 31;
            const int jj = slot & 15;
            const int* sent = sp ? P.sent2 : P.sent1;
            const int* ops = sp ? P.ops2 : P.ops1;
            const int oopl = sp ? *P.oopl2 : *P.oopl1;
            const int t_last = oopl - 1 - Sd;
            const int sidx = ops[b * (Td * 16) + t_last * 16 + jj];
            stok[tid] = sent[b * Sd + sidx];
        }
        __syncthreads();

        float acc[4][4];
#pragma unroll
        for (int j = 0; j < 4; ++j)
#pragma unroll
            for (int i = 0; i < 4; ++i) acc[j][i] = 0.f;

        const int ch0 = kc ? 3 : 0;
        const int ch1 = kc ? 5 : 3;
        for (int ch = ch0; ch < ch1; ++ch) {
            const int kbase = ch * 60;
            for (int u = tid; u < 960; u += 256) {     // A: 64 rows x 15 f4
                const int row = u / 15, k4 = u - row * 15;
                const int tok = stok[row];
                const float* src = (tok >= 0) ? (P.glove + (long)tok * Ed) : P.unk;
                const float4 v = *(const float4*)(src + kbase + k4 * 4);
                Asw[(k4 * 4 + 0) * 68 + row] = v.x;
                Asw[(k4 * 4 + 1) * 68 + row] = v.y;
                Asw[(k4 * 4 + 2) * 68 + row] = v.z;
                Asw[(k4 * 4 + 3) * 68 + row] = v.w;
            }
            for (int u = tid; u < 960; u += 256) {     // B: 64 cols x 15 f4
                const int col = u / 15, k4 = u - col * 15;
                const int gc = cb * 64 + col;
                const int wr = (gc < 256) ? gc : 512 + gc;
                const float4 v = *(const float4*)(P.Wm + (long)wr * Ed + kbase + k4 * 4);
                Bsw[(k4 * 4 + 0) * 68 + col] = v.x;
                Bsw[(k4 * 4 + 1) * 68 + col] = v.y;
                Bsw[(k4 * 4 + 2) * 68 + col] = v.z;
                Bsw[(k4 * 4 + 3) * 68 + col] = v.w;
            }
            __syncthreads();
#pragma unroll 6
            for (int kk = 0; kk < 60; ++kk) {
                const float4 a = *(const float4*)(Asw + kk * 68 + ty * 4);
                const float4 b = *(const float4*)(Bsw + kk * 68 + tx * 4);
                acc[0][0] = fmaf(a.x, b.x, acc[0][0]);
                acc[0][1] = fmaf(a.x, b.y, acc[0][1]);
                acc[0][2] = fmaf(a.x, b.z, acc[0][2]);
                acc[0][3] = fmaf(a.x, b.w, acc[0][3]);
                acc[1][0] = fmaf(a.y, b.x, acc[1][0]);
                acc[1][1] = fmaf(a.y, b.y, acc[1][1]);
                acc[1][2] = fmaf(a.y, b.z, acc[1][2]);
                acc[1][3] = fmaf(a.y, b.w, acc[1][3]);
                acc[2][0] = fmaf(a.z, b.x, acc[2][0]);
                acc[2][1] = fmaf(a.z, b.y, acc[2][1]);
                acc[2][2] = fmaf(a.z, b.z, acc[2][2]);
                acc[2][3] = fmaf(a.z, b.w, acc[2][3]);
                acc[3][0] = fmaf(a.w, b.x, acc[3][0]);
                acc[3][1] = fmaf(a.w, b.y, acc[3][1]);
                acc[3][2] = fmaf(a.w, b.z, acc[3][2]);
                acc[3][3] = fmaf(a.w, b.w, acc[3][3]);
            }
            __syncthreads();
        }

        float* outp0 = kc ? P.p0b : P.p0a;
        const int gc0 = cb * 64 + tx * 4;
        const int wr0 = (gc0 < 256) ? gc0 : 512 + gc0;
        float4 bb = make_float4(0.f, 0.f, 0.f, 0.f);
        if (kc) bb = *(const float4*)(P.bv + wr0);
#pragma unroll
        for (int j = 0; j < 4; ++j) {
            const long row = rb * 64 + ty * 4 + j;
            float4 v;
            v.x = acc[j][0] + bb.x;
            v.y = acc[j][1] + bb.y;
            v.z = acc[j][2] + bb.z;
            v.w = acc[j][3] + bb.w;
            *(float4*)(outp0 + row * 768 + gc0) = v;
        }
    }
    grid.sync();

    // ============ P3: preact1[512][1280] = hh @ U^T, hh built in A-stage ====
    if (blk < 320) {
        const int kc = blk >= 160;
        const int t = kc ? blk - 160 : blk;
        const int rb = t / 20;
        const int cb = t - rb * 20;
        float* Asw = smem;          // [64][68]
        float* Bsw = smem + 4352;   // [64][68]

        float acc[4][4];
#pragma unroll
        for (int j = 0; j < 4; ++j)
#pragma unroll
            for (int i = 0; i < 4; ++i) acc[j][i] = 0.f;

        for (int ch = kc * 4; ch < kc * 4 + 4; ++ch) {
            const int kbase = ch * 64;
            const int jch = kbase >> 8;         // which child (0=L, 1=R)
            const int dbase = kbase & 255;
            for (int u = tid; u < 4096; u += 256) {   // A: hh on the fly
                const int r = u >> 6, k = u & 63;
                const int row = rb * 64 + r;
                const long pb = ((long)(row >> 3) * 16 + (row & 7) * 2 + jch) * 768;
                const int d = dbase + k;
                const float pi = P.p0a[pb + d] + P.p0b[pb + d];
                const float po = P.p0a[pb + 256 + d] + P.p0b[pb + 256 + d];
                const float pu = P.p0a[pb + 512 + d] + P.p0b[pb + 512 + d];
                Asw[k * 68 + r] = sigm(po) * tanhf(sigm(pi) * tanhf(pu));
            }
            for (int u = tid; u < 1024; u += 256) {   // B: 64 cols x 16 f4
                const int col = u >> 4, k4 = u & 15;
                const float4 v = *(const float4*)(P.Um + (long)(cb * 64 + col) * 512 + kbase + k4 * 4);
                Bsw[(k4 * 4 + 0) * 68 + col] = v.x;
                Bsw[(k4 * 4 + 1) * 68 + col] = v.y;
                Bsw[(k4 * 4 + 2) * 68 + col] = v.z;
                Bsw[(k4 * 4 + 3) * 68 + col] = v.w;
            }
            __syncthreads();
#pragma unroll 8
            for (int kk = 0; kk < 64; ++kk) {
                const float4 a = *(const float4*)(Asw + kk * 68 + ty * 4);
                const float4 b = *(const float4*)(Bsw + kk * 68 + tx * 4);
                acc[0][0] = fmaf(a.x, b.x, acc[0][0]);
                acc[0][1] = fmaf(a.x, b.y, acc[0][1]);
                acc[0][2] = fmaf(a.x, b.z, acc[0][2]);
                acc[0][3] = fmaf(a.x, b.w, acc[0][3]);
                acc[1][0] = fmaf(a.y, b.x, acc[1][0]);
                acc[1][1] = fmaf(a.y, b.y, acc[1][1]);
                acc[1][2] = fmaf(a.y, b.z, acc[1][2]);
                acc[1][3] = fmaf(a.y, b.w, acc[1][3]);
                acc[2][0] = fmaf(a.z, b.x, acc[2][0]);
                acc[2][1] = fmaf(a.z, b.y, acc[2][1]);
                acc[2][2] = fmaf(a.z, b.z, acc[2][2]);
                acc[2][3] = fmaf(a.z, b.w, acc[2][3]);
                acc[3][0] = fmaf(a.w, b.x, acc[3][0]);
                acc[3][1] = fmaf(a.w, b.y, acc[3][1]);
                acc[3][2] = fmaf(a.w, b.z, acc[3][2]);
                acc[3][3] = fmaf(a.w, b.w, acc[3][3]);
            }
            __syncthreads();
        }

        float* outp1 = kc ? P.p1b : P.p1a;
        const int gc0 = cb * 64 + tx * 4;
        float4 bb = make_float4(0.f, 0.f, 0.f, 0.f);
        if (kc) bb = *(const float4*)(P.bv + gc0);
#pragma unroll
        for (int j = 0; j < 4; ++j) {
            const long row = rb * 64 + ty * 4 + j;
            float4 v;
            v.x = acc[j][0] + bb.x;
            v.y = acc[j][1] + bb.y;
            v.z = acc[j][2] + bb.z;
            v.w = acc[j][3] + bb.w;
            *(float4*)(outp1 + row * 1280 + gc0) = v;
        }
    }
    grid.sync();

    // ============ P4: gates, norms, energy softmax, combine ================
    if (blk < 64) {
        const int sb = blk;
        const int w = tid >> 6;
        const int lane = tid & 63;
        float* wsq = smem;          // [8][4]
        float* wdt = smem + 32;     // [8][4]
        float* weu = smem + 64;     // [4]

        const float euv = P.eu[tid];
        float r = euv * euv;
        for (int o = 32; o; o >>= 1) r += __shfl_xor(r, o);
        if (lane == 0) weu[w] = r;

        float h[8];
#pragma unroll
        for (int a = 0; a < 8; ++a) {
            const long pb = (long)(sb * 8 + a) * 1280;
            const float gi = sigm(P.p1a[pb + tid] + P.p1b[pb + tid]);
            const float fL = sigm(P.p1a[pb + 256 + tid] + P.p1b[pb + 256 + tid]);
            const float fR = sigm(P.p1a[pb + 512 + tid] + P.p1b[pb + 512 + tid]);
            const float go = sigm(P.p1a[pb + 768 + tid] + P.p1b[pb + 768 + tid]);
            const float gu = tanhf(P.p1a[pb + 1024 + tid] + P.p1b[pb + 1024 + tid]);
            const long pbL = (long)(sb * 16 + 2 * a) * 768;
            const long pbR = pbL + 768;
            const float cL = sigm(P.p0a[pbL + tid] + P.p0b[pbL + tid]) *
                             tanhf(P.p0a[pbL + 512 + tid] + P.p0b[pbL + 512 + tid]);
            const float cR = sigm(P.p0a[pbR + tid] + P.p0b[pbR + tid]) *
                             tanhf(P.p0a[pbR + 512 + tid] + P.p0b[pbR + 512 + tid]);
            const float cc = fL * cL + fR * cR + gi * gu;
            h[a] = go * tanhf(cc);
            float sq = h[a] * h[a];
            float dt = h[a] * euv;
            for (int o = 32; o; o >>= 1) {
                sq += __shfl_xor(sq, o);
                dt += __shfl_xor(dt, o);
            }
            if (lane == 0) { wsq[a * 4 + w] = sq; wdt[a * 4 + w] = dt; }
        }
        __syncthreads();

        const float en = fmaxf(sqrtf(weu[0] + weu[1] + weu[2] + weu[3]), 1e-8f);
        float e[8], m = -1e30f;
#pragma unroll
        for (int a = 0; a < 8; ++a) {
            const float sq = wsq[a * 4 + 0] + wsq[a * 4 + 1] + wsq[a * 4 + 2] + wsq[a * 4 + 3];
            const float dt = wdt[a * 4 + 0] + wdt[a * 4 + 1] + wdt[a * 4 + 2] + wdt[a * 4 + 3];
            const float hn = fmaxf(sqrtf(sq), 1e-8f);
            e[a] = dt / (hn * en);
            m = fmaxf(m, e[a]);
        }
        float sum = 0.f;
#pragma unroll
        for (int a = 0; a < 8; ++a) { e[a] = expf(e[a] - m); sum += e[a]; }
        const float inv = 1.f / sum;
        float comb = 0.f;
#pragma unroll
        for (int a = 0; a < 8; ++a) comb = fmaf(e[a] * inv, h[a], comb);
        P.s_out[(long)sb * 256 + tid] = comb;
    }
    grid.sync();

    // ============ P5: MLP layer-1 + W2 partial logits ======================
    if (blk < 256) {
        const int b = blk >> 3;
        const int mb = blk & 7;
        const int w = tid >> 6, lane = tid & 63;
        float* conc = smem;               // 512 floats
        float4* conc4 = (float4*)smem;
        float* red = smem + 512;          // [4][3]

        conc[tid] = P.s_out[(long)b * 256 + tid];
        conc[256 + tid] = P.s_out[(long)(32 + b) * 256 + tid];
        __syncthreads();

        const float4 ca = conc4[lane * 2];
        const float4 cb_ = conc4[lane * 2 + 1];

        float p0 = 0.f, p1 = 0.f, p2 = 0.f;
        for (int rr = 0; rr < 32; ++rr) {
            const int m = mb * 128 + w * 32 + rr;
            const float4* wr = (const float4*)(P.W1 + (long)m * 512);
            const float4 w0 = wr[lane * 2];
            const float4 w1 = wr[lane * 2 + 1];
            float s = fmaf(ca.x, w0.x, 0.f);
            s = fmaf(ca.y, w0.y, s);
            s = fmaf(ca.z, w0.z, s);
            s = fmaf(ca.w, w0.w, s);
            s = fmaf(cb_.x, w1.x, s);
            s = fmaf(cb_.y, w1.y, s);
            s = fmaf(cb_.z, w1.z, s);
            s = fmaf(cb_.w, w1.w, s);
            for (int o = 32; o; o >>= 1) s += __shfl_xor(s, o);
            const float v = fmaxf(s + P.b1[m], 0.f);
            p0 = fmaf(v, P.W2[m], p0);
            p1 = fmaf(v, P.W2[1024 + m], p1);
            p2 = fmaf(v, P.W2[2048 + m], p2);
        }
        if (lane == 0) { red[w * 3 + 0] = p0; red[w * 3 + 1] = p1; red[w * 3 + 2] = p2; }
        __syncthreads();
        if (tid == 0) {
            const long o = (long)(b * 8 + mb) * 3;
            P.lp[o + 0] = red[0] + red[3] + red[6] + red[9];
            P.lp[o + 1] = red[1] + red[4] + red[7] + red[10];
            P.lp[o + 2] = red[2] + red[5] + red[8] + red[11];
        }
    }
    grid.sync();

    // ============ P6: sum partials, 3-way softmax ==========================
    if (blk == 0 && tid < 32) {
        const int b = tid;
        float l0 = P.b2[0], l1 = P.b2[1], l2 = P.b2[2];
#pragma unroll
        for (int mb = 0; mb < 8; ++mb) {
            const long o = (long)(b * 8 + mb) * 3;
            l0 += P.lp[o + 0];
            l1 += P.lp[o + 1];
            l2 += P.lp[o + 2];
        }
        const float mm = fmaxf(l0, fmaxf(l1, l2));
        const float e0 = expf(l0 - mm), e1 = expf(l1 - mm), e2 = expf(l2 - mm);
        const float inv = 1.f / (e0 + e1 + e2);
        P.outp[b * 3 + 0] = e0 * inv;
        P.outp[b * 3 + 1] = e1 * inv;
        P.outp[b * 3 + 2] = e2 * inv;
    }
}

extern "C" void kernel_launch(void* const* d_in, const int* in_sizes, int n_in,
                              void* d_out, int out_size, void* d_ws, size_t ws_size,
                              hipStream_t stream)
{
    float* ws = (float*)d_ws;

    Params hp;
    hp.sent1 = (const int*)d_in[0];
    hp.ops1 = (const int*)d_in[1];
    hp.oopl1 = (const int*)d_in[2];
    hp.sent2 = (const int*)d_in[3];
    hp.ops2 = (const int*)d_in[4];
    hp.oopl2 = (const int*)d_in[5];
    hp.glove = (const float*)d_in[6];
    hp.Wm = (const float*)d_in[7];
    hp.Um = (const float*)d_in[8];
    hp.bv = (const float*)d_in[9];
    hp.eu = (const float*)d_in[10];
    hp.unk = (const float*)d_in[11];
    hp.W1 = (const float*)d_in[12];
    hp.b1 = (const float*)d_in[13];
    hp.W2 = (const float*)d_in[14];
    hp.b2 = (const float*)d_in[15];
    hp.p0a = ws + OFF_P0A;
    hp.p0b = ws + OFF_P0B;
    hp.p1a = ws + OFF_P1A;
    hp.p1b = ws + OFF_P1B;
    hp.s_out = ws + OFF_SOUT;
    hp.lp = ws + OFF_LP;
    hp.outp = (float*)d_out;

    void* kargs[] = { (void*)&hp };
    hipLaunchCooperativeKernel(k_fused, dim3(384), dim3(256), kargs, 0, stream);
}

// Round 7
// 87.507 us; speedup vs baseline: 3.2487x; 3.2487x over previous
//
#include <hip/hip_runtime.h>
#include <math.h>

#define Ed 300
#define Sd 64
#define Td 64

__device__ __forceinline__ float sigm(float x) { return 1.0f / (1.0f + expf(-x)); }

// ws layout (floats)
#define OFF_P0A   0          // pre0 part0: 1024*768 = 786432
#define OFF_P0B   786432     // pre0 part1 (includes bias)
#define OFF_HH    1572864    // 512*512  = 262144
#define OFF_CLF   1835008    // c_leaf 1024*256 = 262144
#define OFF_P1A   2097152    // preact1 part0: 512*1280 = 655360
#define OFF_P1B   2752512    // preact1 part1 (includes bias)
#define OFF_LP    3407872    // 32*8*3 = 768

// ---------------------------------------------------------------------------
// K1: pre0[1024][768] = gathered_emb[1024][300] @ Wsel[768][300]^T (+bias in
// part1), fused token gather.  Outer-product 4x4 register tile, k-major LDS,
// global->reg prefetch double-buffering across K-chunks.
// Tile 32x64, 128 thr, BK=60, split-K=2.  Grid (384, 2).
// ---------------------------------------------------------------------------
__global__ __launch_bounds__(128) void k_pre0(
    const int* __restrict__ sent1, const int* __restrict__ ops1, const int* __restrict__ oopl1,
    const int* __restrict__ sent2, const int* __restrict__ ops2, const int* __restrict__ oopl2,
    const float* __restrict__ glove, const float* __restrict__ unk,
    const float* __restrict__ Wm, const float* __restrict__ bv, float* __restrict__ pre0base)
{
    const int rb = blockIdx.x / 12;
    const int cb = blockIdx.x - rb * 12;
    const int kc = blockIdx.y;
    const int tid = threadIdx.x;

    __shared__ int stok[32];
    __shared__ float Asw[60 * 36];   // [kk][row]
    __shared__ float Bsw[60 * 68];   // [kk][col]

    if (tid < 32) {
        const int slot = rb * 32 + tid;
        const int sp = slot >> 9;
        const int b = (slot >> 4) & 31;
        const int j = slot & 15;
        const int* sent = sp ? sent2 : sent1;
        const int* ops = sp ? ops2 : ops1;
        const int oopl = sp ? *oopl2 : *oopl1;
        const int t_last = oopl - 1 - Sd;
        const int sidx = ops[b * (Td * 16) + t_last * 16 + j];
        stok[tid] = sent[b * Sd + sidx];
    }
    __syncthreads();

    const int tx = tid & 15;
    const int ty = tid >> 4;

    // per-thread staging element coords
    int arow[4], ak4[4], bcol[8], bk4[8];
#pragma unroll
    for (int i = 0; i < 4; ++i) {
        const int idx = tid + 128 * i;
        arow[i] = idx / 15; ak4[i] = idx - arow[i] * 15;
    }
#pragma unroll
    for (int i = 0; i < 8; ++i) {
        const int idx = tid + 128 * i;
        bcol[i] = idx / 15; bk4[i] = idx - bcol[i] * 15;
    }

    float acc[4][4];
#pragma unroll
    for (int j = 0; j < 4; ++j)
#pragma unroll
        for (int i = 0; i < 4; ++i) acc[j][i] = 0.f;

    const int ch0 = kc ? 3 : 0;
    const int ch1 = kc ? 5 : 3;

    float4 pa[4], pb[8];
    // prologue: load first chunk
    {
        const int kbase = ch0 * 60;
#pragma unroll
        for (int i = 0; i < 4; ++i)
            if (tid + 128 * i < 480) {
                const int tok = stok[arow[i]];
                const float* src = (tok >= 0) ? (glove + (long)tok * Ed) : unk;
                pa[i] = *(const float4*)(src + kbase + ak4[i] * 4);
            }
#pragma unroll
        for (int i = 0; i < 8; ++i)
            if (tid + 128 * i < 960) {
                const int gc = cb * 64 + bcol[i];
                const int wr = (gc < 256) ? gc : 512 + gc;
                pb[i] = *(const float4*)(Wm + (long)wr * Ed + kbase + bk4[i] * 4);
            }
    }

    for (int ch = ch0; ch < ch1; ++ch) {
        // store staged regs to LDS
#pragma unroll
        for (int i = 0; i < 4; ++i)
            if (tid + 128 * i < 480) {
                Asw[(ak4[i] * 4 + 0) * 36 + arow[i]] = pa[i].x;
                Asw[(ak4[i] * 4 + 1) * 36 + arow[i]] = pa[i].y;
                Asw[(ak4[i] * 4 + 2) * 36 + arow[i]] = pa[i].z;
                Asw[(ak4[i] * 4 + 3) * 36 + arow[i]] = pa[i].w;
            }
#pragma unroll
        for (int i = 0; i < 8; ++i)
            if (tid + 128 * i < 960) {
                Bsw[(bk4[i] * 4 + 0) * 68 + bcol[i]] = pb[i].x;
                Bsw[(bk4[i] * 4 + 1) * 68 + bcol[i]] = pb[i].y;
                Bsw[(bk4[i] * 4 + 2) * 68 + bcol[i]] = pb[i].z;
                Bsw[(bk4[i] * 4 + 3) * 68 + bcol[i]] = pb[i].w;
            }
        __syncthreads();
        // issue next chunk's loads (overlap with FMA below)
        if (ch + 1 < ch1) {
            const int kbase = (ch + 1) * 60;
#pragma unroll
            for (int i = 0; i < 4; ++i)
                if (tid + 128 * i < 480) {
                    const int tok = stok[arow[i]];
                    const float* src = (tok >= 0) ? (glove + (long)tok * Ed) : unk;
                    pa[i] = *(const float4*)(src + kbase + ak4[i] * 4);
                }
#pragma unroll
            for (int i = 0; i < 8; ++i)
                if (tid + 128 * i < 960) {
                    const int gc = cb * 64 + bcol[i];
                    const int wr = (gc < 256) ? gc : 512 + gc;
                    pb[i] = *(const float4*)(Wm + (long)wr * Ed + kbase + bk4[i] * 4);
                }
        }
#pragma unroll 6
        for (int kk = 0; kk < 60; ++kk) {
            const float4 a = *(const float4*)(Asw + kk * 36 + ty * 4);
            const float4 b = *(const float4*)(Bsw + kk * 68 + tx * 4);
            acc[0][0] = fmaf(a.x, b.x, acc[0][0]);
            acc[0][1] = fmaf(a.x, b.y, acc[0][1]);
            acc[0][2] = fmaf(a.x, b.z, acc[0][2]);
            acc[0][3] = fmaf(a.x, b.w, acc[0][3]);
            acc[1][0] = fmaf(a.y, b.x, acc[1][0]);
            acc[1][1] = fmaf(a.y, b.y, acc[1][1]);
            acc[1][2] = fmaf(a.y, b.z, acc[1][2]);
            acc[1][3] = fmaf(a.y, b.w, acc[1][3]);
            acc[2][0] = fmaf(a.z, b.x, acc[2][0]);
            acc[2][1] = fmaf(a.z, b.y, acc[2][1]);
            acc[2][2] = fmaf(a.z, b.z, acc[2][2]);
            acc[2][3] = fmaf(a.z, b.w, acc[2][3]);
            acc[3][0] = fmaf(a.w, b.x, acc[3][0]);
            acc[3][1] = fmaf(a.w, b.y, acc[3][1]);
            acc[3][2] = fmaf(a.w, b.z, acc[3][2]);
            acc[3][3] = fmaf(a.w, b.w, acc[3][3]);
        }
        __syncthreads();
    }

    float* outp = pre0base + (kc ? OFF_P0B : OFF_P0A);
    const int gc0 = cb * 64 + tx * 4;
    const int wr0 = (gc0 < 256) ? gc0 : 512 + gc0;
    float4 bb = make_float4(0.f, 0.f, 0.f, 0.f);
    if (kc) bb = *(const float4*)(bv + wr0);
#pragma unroll
    for (int j = 0; j < 4; ++j) {
        const long row = rb * 32 + ty * 4 + j;
        float4 v;
        v.x = acc[j][0] + bb.x;
        v.y = acc[j][1] + bb.y;
        v.z = acc[j][2] + bb.z;
        v.w = acc[j][3] + bb.w;
        *(float4*)(outp + row * 768 + gc0) = v;
    }
}

// ---------------------------------------------------------------------------
// K2: leaf gates -> hh[512][512] and c_leaf[1024][256], fully float4.
// Grid = 256 WGs x 256 thr; one f4 of one slot per thread.
// ---------------------------------------------------------------------------
__global__ __launch_bounds__(256) void k_hh(
    const float* __restrict__ p0a, const float* __restrict__ p0b,
    float* __restrict__ hh, float* __restrict__ c_leaf)
{
    const int gid = blockIdx.x * 256 + threadIdx.x;   // 0..65535
    const int slot = gid >> 6;
    const int d = (gid & 63) * 4;
    const long pb = (long)slot * 768;
    const float4 ia = *(const float4*)(p0a + pb + d);
    const float4 ib = *(const float4*)(p0b + pb + d);
    const float4 oa = *(const float4*)(p0a + pb + 256 + d);
    const float4 ob = *(const float4*)(p0b + pb + 256 + d);
    const float4 ua = *(const float4*)(p0a + pb + 512 + d);
    const float4 ub = *(const float4*)(p0b + pb + 512 + d);
    float4 c0, h0;
    c0.x = sigm(ia.x + ib.x) * tanhf(ua.x + ub.x);
    c0.y = sigm(ia.y + ib.y) * tanhf(ua.y + ub.y);
    c0.z = sigm(ia.z + ib.z) * tanhf(ua.z + ub.z);
    c0.w = sigm(ia.w + ib.w) * tanhf(ua.w + ub.w);
    h0.x = sigm(oa.x + ob.x) * tanhf(c0.x);
    h0.y = sigm(oa.y + ob.y) * tanhf(c0.y);
    h0.z = sigm(oa.z + ob.z) * tanhf(c0.z);
    h0.w = sigm(oa.w + ob.w) * tanhf(c0.w);
    *(float4*)(c_leaf + (long)slot * 256 + d) = c0;
    const int j = slot & 1;
    const int row = ((slot >> 4) << 3) + ((slot >> 1) & 7);
    *(float4*)(hh + (long)row * 512 + j * 256 + d) = h0;
}

// ---------------------------------------------------------------------------
// K3: preact1[512][1280] = hh @ U^T (+bias in part1).  Outer-product 4x4,
// k-major LDS, reg prefetch.  Tile 32x64, 128 thr, BK=64, split-K=2.
// Grid (320, 2).
// ---------------------------------------------------------------------------
__global__ __launch_bounds__(128) void k_g2(
    const float* __restrict__ hh, const float* __restrict__ Um, const float* __restrict__ bv,
    float* __restrict__ pre1base)
{
    const int rb = blockIdx.x / 20;
    const int cb = blockIdx.x - rb * 20;
    const int kc = blockIdx.y;
    const int tid = threadIdx.x;

    __shared__ float Asw[64 * 36];
    __shared__ float Bsw[64 * 68];

    const int tx = tid & 15;
    const int ty = tid >> 4;

    float acc[4][4];
#pragma unroll
    for (int j = 0; j < 4; ++j)
#pragma unroll
        for (int i = 0; i < 4; ++i) acc[j][i] = 0.f;

    const int ch0 = kc * 4;
    float4 pa[4], pb[8];
    {
        const int kbase = ch0 * 64;
#pragma unroll
        for (int i = 0; i < 4; ++i) {
            const int idx = tid + 128 * i;
            pa[i] = *(const float4*)(hh + (long)(rb * 32 + (idx >> 4)) * 512 + kbase + (idx & 15) * 4);
        }
#pragma unroll
        for (int i = 0; i < 8; ++i) {
            const int idx = tid + 128 * i;
            pb[i] = *(const float4*)(Um + (long)(cb * 64 + (idx >> 4)) * 512 + kbase + (idx & 15) * 4);
        }
    }

    for (int ch = ch0; ch < ch0 + 4; ++ch) {
#pragma unroll
        for (int i = 0; i < 4; ++i) {
            const int idx = tid + 128 * i;
            const int row = idx >> 4, k4 = idx & 15;
            Asw[(k4 * 4 + 0) * 36 + row] = pa[i].x;
            Asw[(k4 * 4 + 1) * 36 + row] = pa[i].y;
            Asw[(k4 * 4 + 2) * 36 + row] = pa[i].z;
            Asw[(k4 * 4 + 3) * 36 + row] = pa[i].w;
        }
#pragma unroll
        for (int i = 0; i < 8; ++i) {
            const int idx = tid + 128 * i;
            const int col = idx >> 4, k4 = idx & 15;
            Bsw[(k4 * 4 + 0) * 68 + col] = pb[i].x;
            Bsw[(k4 * 4 + 1) * 68 + col] = pb[i].y;
            Bsw[(k4 * 4 + 2) * 68 + col] = pb[i].z;
            Bsw[(k4 * 4 + 3) * 68 + col] = pb[i].w;
        }
        __syncthreads();
        if (ch + 1 < ch0 + 4) {
            const int kbase = (ch + 1) * 64;
#pragma unroll
            for (int i = 0; i < 4; ++i) {
                const int idx = tid + 128 * i;
                pa[i] = *(const float4*)(hh + (long)(rb * 32 + (idx >> 4)) * 512 + kbase + (idx & 15) * 4);
            }
#pragma unroll
            for (int i = 0; i < 8; ++i) {
                const int idx = tid + 128 * i;
                pb[i] = *(const float4*)(Um + (long)(cb * 64 + (idx >> 4)) * 512 + kbase + (idx & 15) * 4);
            }
        }
#pragma unroll 8
        for (int kk = 0; kk < 64; ++kk) {
            const float4 a = *(const float4*)(Asw + kk * 36 + ty * 4);
            const float4 b = *(const float4*)(Bsw + kk * 68 + tx * 4);
            acc[0][0] = fmaf(a.x, b.x, acc[0][0]);
            acc[0][1] = fmaf(a.x, b.y, acc[0][1]);
            acc[0][2] = fmaf(a.x, b.z, acc[0][2]);
            acc[0][3] = fmaf(a.x, b.w, acc[0][3]);
            acc[1][0] = fmaf(a.y, b.x, acc[1][0]);
            acc[1][1] = fmaf(a.y, b.y, acc[1][1]);
            acc[1][2] = fmaf(a.y, b.z, acc[1][2]);
            acc[1][3] = fmaf(a.y, b.w, acc[1][3]);
            acc[2][0] = fmaf(a.z, b.x, acc[2][0]);
            acc[2][1] = fmaf(a.z, b.y, acc[2][1]);
            acc[2][2] = fmaf(a.z, b.z, acc[2][2]);
            acc[2][3] = fmaf(a.z, b.w, acc[2][3]);
            acc[3][0] = fmaf(a.w, b.x, acc[3][0]);
            acc[3][1] = fmaf(a.w, b.y, acc[3][1]);
            acc[3][2] = fmaf(a.w, b.z, acc[3][2]);
            acc[3][3] = fmaf(a.w, b.w, acc[3][3]);
        }
        __syncthreads();
    }

    float* outp = pre1base + (kc ? (OFF_P1B - OFF_P1A) : 0);
    const int gc0 = cb * 64 + tx * 4;
    float4 bb = make_float4(0.f, 0.f, 0.f, 0.f);
    if (kc) bb = *(const float4*)(bv + gc0);
#pragma unroll
    for (int j = 0; j < 4; ++j) {
        const long row = rb * 32 + ty * 4 + j;
        float4 v;
        v.x = acc[j][0] + bb.x;
        v.y = acc[j][1] + bb.y;
        v.z = acc[j][2] + bb.z;
        v.w = acc[j][3] + bb.w;
        *(float4*)(outp + row * 1280 + gc0) = v;
    }
}

// ---------------------------------------------------------------------------
// K4: tail.  Each block (b, mb) redundantly computes the s_out pair for
// batch b in LDS (gates+norms+softmax+combine), then does MLP rows
// mb*128..mb*128+127 and writes partial logits.  Grid = 256 x 256 thr.
// ---------------------------------------------------------------------------
__global__ __launch_bounds__(256) void k_tail(
    const float* __restrict__ p1a, const float* __restrict__ p1b,
    const float* __restrict__ c_leaf, const float* __restrict__ eu,
    const float* __restrict__ W1, const float* __restrict__ b1,
    const float* __restrict__ W2, float* __restrict__ lp)
{
    const int b = blockIdx.x >> 3;
    const int mb = blockIdx.x & 7;
    const int tid = threadIdx.x;
    const int w = tid >> 6, lane = tid & 63;

    __shared__ float conc[512];
    __shared__ float wsq[8][4], wdt[8][4], weu[4], red[4][3];

    const float euv = eu[tid];
    float r = euv * euv;
    for (int o = 32; o; o >>= 1) r += __shfl_xor(r, o);
    if (lane == 0) weu[w] = r;

#pragma unroll
    for (int half = 0; half < 2; ++half) {
        const int sb = half * 32 + b;
        float h[8];
#pragma unroll
        for (int a = 0; a < 8; ++a) {
            const long pb = (long)(sb * 8 + a) * 1280;
            const float gi = sigm(p1a[pb + tid] + p1b[pb + tid]);
            const float fL = sigm(p1a[pb + 256 + tid] + p1b[pb + 256 + tid]);
            const float fR = sigm(p1a[pb + 512 + tid] + p1b[pb + 512 + tid]);
            const float go = sigm(p1a[pb + 768 + tid] + p1b[pb + 768 + tid]);
            const float gu = tanhf(p1a[pb + 1024 + tid] + p1b[pb + 1024 + tid]);
            const long cl = (long)(sb * 16 + 2 * a) * 256;
            const float cL = c_leaf[cl + tid];
            const float cR = c_leaf[cl + 256 + tid];
            const float cc = fL * cL + fR * cR + gi * gu;
            h[a] = go * tanhf(cc);
            float sq = h[a] * h[a];
            float dt = h[a] * euv;
            for (int o = 32; o; o >>= 1) {
                sq += __shfl_xor(sq, o);
                dt += __shfl_xor(dt, o);
            }
            if (lane == 0) { wsq[a][w] = sq; wdt[a][w] = dt; }
        }
        __syncthreads();

        const float en = fmaxf(sqrtf(weu[0] + weu[1] + weu[2] + weu[3]), 1e-8f);
        float e[8], m = -1e30f;
#pragma unroll
        for (int a = 0; a < 8; ++a) {
            const float sq = wsq[a][0] + wsq[a][1] + wsq[a][2] + wsq[a][3];
            const float dt = wdt[a][0] + wdt[a][1] + wdt[a][2] + wdt[a][3];
            const float hn = fmaxf(sqrtf(sq), 1e-8f);
            e[a] = dt / (hn * en);
            m = fmaxf(m, e[a]);
        }
        float sum = 0.f;
#pragma unroll
        for (int a = 0; a < 8; ++a) { e[a] = expf(e[a] - m); sum += e[a]; }
        const float inv = 1.f / sum;
        float comb = 0.f;
#pragma unroll
        for (int a = 0; a < 8; ++a) comb = fmaf(e[a] * inv, h[a], comb);
        conc[half * 256 + tid] = comb;
        __syncthreads();
    }

    // MLP phase: rows mb*128 .. +127, one row per wave iteration
    const float4* conc4 = (const float4*)conc;
    const float4 ca = conc4[lane * 2];
    const float4 cb_ = conc4[lane * 2 + 1];

    float p0 = 0.f, p1 = 0.f, p2 = 0.f;
    for (int rr = 0; rr < 32; ++rr) {
        const int m = mb * 128 + w * 32 + rr;
        const float4* wr = (const float4*)(W1 + (long)m * 512);
        const float4 w0 = wr[lane * 2];
        const float4 w1 = wr[lane * 2 + 1];
        float s = fmaf(ca.x, w0.x, 0.f);
        s = fmaf(ca.y, w0.y, s);
        s = fmaf(ca.z, w0.z, s);
        s = fmaf(ca.w, w0.w, s);
        s = fmaf(cb_.x, w1.x, s);
        s = fmaf(cb_.y, w1.y, s);
        s = fmaf(cb_.z, w1.z, s);
        s = fmaf(cb_.w, w1.w, s);
        for (int o = 32; o; o >>= 1) s += __shfl_xor(s, o);
        const float v = fmaxf(s + b1[m], 0.f);
        p0 = fmaf(v, W2[m], p0);
        p1 = fmaf(v, W2[1024 + m], p1);
        p2 = fmaf(v, W2[2048 + m], p2);
    }
    if (lane == 0) { red[w][0] = p0; red[w][1] = p1; red[w][2] = p2; }
    __syncthreads();
    if (tid == 0) {
        const long o = (long)(b * 8 + mb) * 3;
        lp[o + 0] = red[0][0] + red[1][0] + red[2][0] + red[3][0];
        lp[o + 1] = red[0][1] + red[1][1] + red[2][1] + red[3][1];
        lp[o + 2] = red[0][2] + red[1][2] + red[2][2] + red[3][2];
    }
}

// ---------------------------------------------------------------------------
// K5: sum logit partials, 3-way softmax.  Grid = 1 WG x 64 thr.
// ---------------------------------------------------------------------------
__global__ __launch_bounds__(64) void k_out(
    const float* __restrict__ lp, const float* __restrict__ b2, float* __restrict__ outp)
{
    const int b = threadIdx.x;
    if (b < 32) {
        float l0 = b2[0], l1 = b2[1], l2 = b2[2];
#pragma unroll
        for (int mb = 0; mb < 8; ++mb) {
            const long o = (long)(b * 8 + mb) * 3;
            l0 += lp[o + 0];
            l1 += lp[o + 1];
            l2 += lp[o + 2];
        }
        const float mm = fmaxf(l0, fmaxf(l1, l2));
        const float e0 = expf(l0 - mm), e1 = expf(l1 - mm), e2 = expf(l2 - mm);
        const float inv = 1.f / (e0 + e1 + e2);
        outp[b * 3 + 0] = e0 * inv;
        outp[b * 3 + 1] = e1 * inv;
        outp[b * 3 + 2] = e2 * inv;
    }
}

extern "C" void kernel_launch(void* const* d_in, const int* in_sizes, int n_in,
                              void* d_out, int out_size, void* d_ws, size_t ws_size,
                              hipStream_t stream)
{
    const int* sent1 = (const int*)d_in[0];
    const int* ops1 = (const int*)d_in[1];
    const int* oopl1 = (const int*)d_in[2];
    const int* sent2 = (const int*)d_in[3];
    const int* ops2 = (const int*)d_in[4];
    const int* oopl2 = (const int*)d_in[5];
    const float* glove = (const float*)d_in[6];
    const float* Wm = (const float*)d_in[7];
    const float* Um = (const float*)d_in[8];
    const float* bv = (const float*)d_in[9];
    const float* eu = (const float*)d_in[10];
    const float* unk = (const float*)d_in[11];
    const float* W1 = (const float*)d_in[12];
    const float* b1 = (const float*)d_in[13];
    const float* W2 = (const float*)d_in[14];
    const float* b2 = (const float*)d_in[15];
    float* outp = (float*)d_out;

    float* ws = (float*)d_ws;
    float* p0a = ws + OFF_P0A;
    float* p0b = ws + OFF_P0B;
    float* hh = ws + OFF_HH;
    float* c_leaf = ws + OFF_CLF;
    float* p1a = ws + OFF_P1A;
    float* p1b = ws + OFF_P1B;
    float* lp = ws + OFF_LP;

    hipLaunchKernelGGL(k_pre0, dim3(384, 2), dim3(128), 0, stream,
                       sent1, ops1, oopl1, sent2, ops2, oopl2, glove, unk, Wm, bv, ws);
    hipLaunchKernelGGL(k_hh, dim3(256), dim3(256), 0, stream, p0a, p0b, hh, c_leaf);
    hipLaunchKernelGGL(k_g2, dim3(320, 2), dim3(128), 0, stream, hh, Um, bv, p1a);
    hipLaunchKernelGGL(k_tail, dim3(256), dim3(256), 0, stream,
                       p1a, p1b, c_leaf, eu, W1, b1, W2, lp);
    hipLaunchKernelGGL(k_out, dim3(1), dim3(64), 0, stream, lp, b2, outp);
}

// Round 8
// 81.098 us; speedup vs baseline: 3.5055x; 1.0790x over previous
//
#include <hip/hip_runtime.h>
#include <math.h>

#define Ed 300
#define Sd 64
#define Td 64

__device__ __forceinline__ float sigm(float x) { return 1.0f / (1.0f + expf(-x)); }

// ws layout (floats)
#define OFF_P0    0          // pre0 parts: 5 x 786432 = 3932160
#define P0_STRIDE 786432
#define OFF_HH    3932160    // 512*512  = 262144
#define OFF_CLF   4194304    // c_leaf 1024*256 = 262144
#define OFF_P1    4456448    // preact1 parts: 4 x 655360 = 2621440
#define P1_STRIDE 655360
#define OFF_SOUT  7077888    // 64*256 = 16384
#define OFF_LP    7094272    // 32*16*3 = 1536
#define OFF_CTR   7095808    // 1 int

// ---------------------------------------------------------------------------
// K1: pre0 partial products.  part[kc][1024][768] = emb_chunk @ Wsel_chunk^T,
// kc in [0,5), BK=60 each (no bias; k_hh adds it).  Fused token gather.
// Outer-product 4x4 register tile, k-major LDS.  Tile 32x64, 128 thr.
// Grid (384, 5).
// ---------------------------------------------------------------------------
__global__ __launch_bounds__(128) void k_pre0(
    const int* __restrict__ sent1, const int* __restrict__ ops1, const int* __restrict__ oopl1,
    const int* __restrict__ sent2, const int* __restrict__ ops2, const int* __restrict__ oopl2,
    const float* __restrict__ glove, const float* __restrict__ unk,
    const float* __restrict__ Wm, float* __restrict__ p0base)
{
    const int rb = blockIdx.x / 12;
    const int cb = blockIdx.x - rb * 12;
    const int kc = blockIdx.y;          // 0..4
    const int kbase = kc * 60;
    const int tid = threadIdx.x;

    __shared__ int stok[32];
    __shared__ float Asw[60 * 36];   // [kk][row]
    __shared__ float Bsw[60 * 68];   // [kk][col]

    if (tid < 32) {
        const int slot = rb * 32 + tid;
        const int sp = slot >> 9;
        const int b = (slot >> 4) & 31;
        const int j = slot & 15;
        const int* sent = sp ? sent2 : sent1;
        const int* ops = sp ? ops2 : ops1;
        const int oopl = sp ? *oopl2 : *oopl1;
        const int t_last = oopl - 1 - Sd;
        const int sidx = ops[b * (Td * 16) + t_last * 16 + j];
        stok[tid] = sent[b * Sd + sidx];
    }
    __syncthreads();

    for (int u = tid; u < 480; u += 128) {
        const int row = u / 15, k4 = u - row * 15;
        const int tok = stok[row];
        const float* src = (tok >= 0) ? (glove + (long)tok * Ed) : unk;
        const float4 v = *(const float4*)(src + kbase + k4 * 4);
        Asw[(k4 * 4 + 0) * 36 + row] = v.x;
        Asw[(k4 * 4 + 1) * 36 + row] = v.y;
        Asw[(k4 * 4 + 2) * 36 + row] = v.z;
        Asw[(k4 * 4 + 3) * 36 + row] = v.w;
    }
    for (int u = tid; u < 960; u += 128) {
        const int col = u / 15, k4 = u - col * 15;
        const int gc = cb * 64 + col;
        const int wr = (gc < 256) ? gc : 512 + gc;
        const float4 v = *(const float4*)(Wm + (long)wr * Ed + kbase + k4 * 4);
        Bsw[(k4 * 4 + 0) * 68 + col] = v.x;
        Bsw[(k4 * 4 + 1) * 68 + col] = v.y;
        Bsw[(k4 * 4 + 2) * 68 + col] = v.z;
        Bsw[(k4 * 4 + 3) * 68 + col] = v.w;
    }
    __syncthreads();

    const int tx = tid & 15;
    const int ty = tid >> 4;
    float acc[4][4];
#pragma unroll
    for (int j = 0; j < 4; ++j)
#pragma unroll
        for (int i = 0; i < 4; ++i) acc[j][i] = 0.f;

#pragma unroll 6
    for (int kk = 0; kk < 60; ++kk) {
        const float4 a = *(const float4*)(Asw + kk * 36 + ty * 4);
        const float4 b = *(const float4*)(Bsw + kk * 68 + tx * 4);
        acc[0][0] = fmaf(a.x, b.x, acc[0][0]);
        acc[0][1] = fmaf(a.x, b.y, acc[0][1]);
        acc[0][2] = fmaf(a.x, b.z, acc[0][2]);
        acc[0][3] = fmaf(a.x, b.w, acc[0][3]);
        acc[1][0] = fmaf(a.y, b.x, acc[1][0]);
        acc[1][1] = fmaf(a.y, b.y, acc[1][1]);
        acc[1][2] = fmaf(a.y, b.z, acc[1][2]);
        acc[1][3] = fmaf(a.y, b.w, acc[1][3]);
        acc[2][0] = fmaf(a.z, b.x, acc[2][0]);
        acc[2][1] = fmaf(a.z, b.y, acc[2][1]);
        acc[2][2] = fmaf(a.z, b.z, acc[2][2]);
        acc[2][3] = fmaf(a.z, b.w, acc[2][3]);
        acc[3][0] = fmaf(a.w, b.x, acc[3][0]);
        acc[3][1] = fmaf(a.w, b.y, acc[3][1]);
        acc[3][2] = fmaf(a.w, b.z, acc[3][2]);
        acc[3][3] = fmaf(a.w, b.w, acc[3][3]);
    }

    float* outp = p0base + (long)kc * P0_STRIDE;
    const int gc0 = cb * 64 + tx * 4;
#pragma unroll
    for (int j = 0; j < 4; ++j) {
        const long row = rb * 32 + ty * 4 + j;
        *(float4*)(outp + row * 768 + gc0) = make_float4(acc[j][0], acc[j][1], acc[j][2], acc[j][3]);
    }
}

__device__ __forceinline__ float4 add4(float4 a, float4 b) {
    return make_float4(a.x + b.x, a.y + b.y, a.z + b.z, a.w + b.w);
}

// ---------------------------------------------------------------------------
// K2: sum 5 pre0 parts + bias -> leaf gates -> hh[512][512], c_leaf[1024][256].
// Grid = 256 WGs x 256 thr; one f4 of one slot per thread.
// ---------------------------------------------------------------------------
__global__ __launch_bounds__(256) void k_hh(
    const float* __restrict__ p0base, const float* __restrict__ bv,
    float* __restrict__ hh, float* __restrict__ c_leaf)
{
    const int gid = blockIdx.x * 256 + threadIdx.x;   // 0..65535
    const int slot = gid >> 6;
    const int d = (gid & 63) * 4;
    const long pb = (long)slot * 768;

    float4 si = *(const float4*)(bv + d);
    float4 so = *(const float4*)(bv + 768 + d);
    float4 su = *(const float4*)(bv + 1024 + d);
#pragma unroll
    for (int p = 0; p < 5; ++p) {
        const float* base = p0base + (long)p * P0_STRIDE + pb;
        si = add4(si, *(const float4*)(base + d));
        so = add4(so, *(const float4*)(base + 256 + d));
        su = add4(su, *(const float4*)(base + 512 + d));
    }
    float4 c0, h0;
    c0.x = sigm(si.x) * tanhf(su.x);
    c0.y = sigm(si.y) * tanhf(su.y);
    c0.z = sigm(si.z) * tanhf(su.z);
    c0.w = sigm(si.w) * tanhf(su.w);
    h0.x = sigm(so.x) * tanhf(c0.x);
    h0.y = sigm(so.y) * tanhf(c0.y);
    h0.z = sigm(so.z) * tanhf(c0.z);
    h0.w = sigm(so.w) * tanhf(c0.w);
    *(float4*)(c_leaf + (long)slot * 256 + d) = c0;
    const int j = slot & 1;
    const int row = ((slot >> 4) << 3) + ((slot >> 1) & 7);
    *(float4*)(hh + (long)row * 512 + j * 256 + d) = h0;
}

// ---------------------------------------------------------------------------
// K3: preact1 partial products.  part[kc][512][1280] = hh_chunk @ U_chunk^T,
// kc in [0,4), 2 x BK=64 chunks each (no bias; k_finish adds it).
// Outer-product 4x4, k-major LDS.  Tile 32x64, 128 thr.  Grid (320, 4).
// ---------------------------------------------------------------------------
__global__ __launch_bounds__(128) void k_g2(
    const float* __restrict__ hh, const float* __restrict__ Um, float* __restrict__ p1base)
{
    const int rb = blockIdx.x / 20;
    const int cb = blockIdx.x - rb * 20;
    const int kc = blockIdx.y;          // 0..3
    const int tid = threadIdx.x;

    __shared__ float Asw[64 * 36];
    __shared__ float Bsw[64 * 68];

    const int tx = tid & 15;
    const int ty = tid >> 4;

    float acc[4][4];
#pragma unroll
    for (int j = 0; j < 4; ++j)
#pragma unroll
        for (int i = 0; i < 4; ++i) acc[j][i] = 0.f;

#pragma unroll
    for (int ch = 0; ch < 2; ++ch) {
        const int kbase = kc * 128 + ch * 64;
#pragma unroll
        for (int it = 0; it < 4; ++it) {   // A: 32 rows x 16 f4
            const int u = tid + 128 * it;
            const int row = u >> 4, k4 = u & 15;
            const float4 v = *(const float4*)(hh + (long)(rb * 32 + row) * 512 + kbase + k4 * 4);
            Asw[(k4 * 4 + 0) * 36 + row] = v.x;
            Asw[(k4 * 4 + 1) * 36 + row] = v.y;
            Asw[(k4 * 4 + 2) * 36 + row] = v.z;
            Asw[(k4 * 4 + 3) * 36 + row] = v.w;
        }
#pragma unroll
        for (int it = 0; it < 8; ++it) {   // B: 64 cols x 16 f4
            const int u = tid + 128 * it;
            const int col = u >> 4, k4 = u & 15;
            const float4 v = *(const float4*)(Um + (long)(cb * 64 + col) * 512 + kbase + k4 * 4);
            Bsw[(k4 * 4 + 0) * 68 + col] = v.x;
            Bsw[(k4 * 4 + 1) * 68 + col] = v.y;
            Bsw[(k4 * 4 + 2) * 68 + col] = v.z;
            Bsw[(k4 * 4 + 3) * 68 + col] = v.w;
        }
        __syncthreads();
#pragma unroll 8
        for (int kk = 0; kk < 64; ++kk) {
            const float4 a = *(const float4*)(Asw + kk * 36 + ty * 4);
            const float4 b = *(const float4*)(Bsw + kk * 68 + tx * 4);
            acc[0][0] = fmaf(a.x, b.x, acc[0][0]);
            acc[0][1] = fmaf(a.x, b.y, acc[0][1]);
            acc[0][2] = fmaf(a.x, b.z, acc[0][2]);
            acc[0][3] = fmaf(a.x, b.w, acc[0][3]);
            acc[1][0] = fmaf(a.y, b.x, acc[1][0]);
            acc[1][1] = fmaf(a.y, b.y, acc[1][1]);
            acc[1][2] = fmaf(a.y, b.z, acc[1][2]);
            acc[1][3] = fmaf(a.y, b.w, acc[1][3]);
            acc[2][0] = fmaf(a.z, b.x, acc[2][0]);
            acc[2][1] = fmaf(a.z, b.y, acc[2][1]);
            acc[2][2] = fmaf(a.z, b.z, acc[2][2]);
            acc[2][3] = fmaf(a.z, b.w, acc[2][3]);
            acc[3][0] = fmaf(a.w, b.x, acc[3][0]);
            acc[3][1] = fmaf(a.w, b.y, acc[3][1]);
            acc[3][2] = fmaf(a.w, b.z, acc[3][2]);
            acc[3][3] = fmaf(a.w, b.w, acc[3][3]);
        }
        __syncthreads();
    }

    float* outp = p1base + (long)kc * P1_STRIDE;
    const int gc0 = cb * 64 + tx * 4;
#pragma unroll
    for (int j = 0; j < 4; ++j) {
        const long row = rb * 32 + ty * 4 + j;
        *(float4*)(outp + row * 1280 + gc0) = make_float4(acc[j][0], acc[j][1], acc[j][2], acc[j][3]);
    }
}

// ---------------------------------------------------------------------------
// K4: sum 4 preact1 parts + bias -> gates, h-norms, energies, softmax,
// combine -> s_out.  Also zeroes the mlp completion counter.
// Grid = 64 WGs (sb) x 256 thr (d).
// ---------------------------------------------------------------------------
__global__ __launch_bounds__(256) void k_finish(
    const float* __restrict__ p1base, const float* __restrict__ bv,
    const float* __restrict__ c_leaf, const float* __restrict__ eu,
    float* __restrict__ s_out, int* __restrict__ ctr)
{
    const int sb = blockIdx.x;
    const int tid = threadIdx.x;
    const int w = tid >> 6;
    const int lane = tid & 63;
    if (sb == 0 && tid == 0) *ctr = 0;

    __shared__ float wsq[8][4], wdt[8][4], weu[4];

    const float euv = eu[tid];
    float r = euv * euv;
    for (int o = 32; o; o >>= 1) r += __shfl_xor(r, o);
    if (lane == 0) weu[w] = r;

    float h[8];
#pragma unroll
    for (int a = 0; a < 8; ++a) {
        const long pb = (long)(sb * 8 + a) * 1280;
        float g[5];
#pragma unroll
        for (int q = 0; q < 5; ++q) {
            float s = bv[q * 256 + tid];
#pragma unroll
            for (int p = 0; p < 4; ++p) s += p1base[(long)p * P1_STRIDE + pb + q * 256 + tid];
            g[q] = s;
        }
        const float gi = sigm(g[0]);
        const float fL = sigm(g[1]);
        const float fR = sigm(g[2]);
        const float go = sigm(g[3]);
        const float gu = tanhf(g[4]);
        const long cl = (long)(sb * 16 + 2 * a) * 256;
        const float cL = c_leaf[cl + tid];
        const float cR = c_leaf[cl + 256 + tid];
        const float cc = fL * cL + fR * cR + gi * gu;
        h[a] = go * tanhf(cc);
        float sq = h[a] * h[a];
        float dt = h[a] * euv;
        for (int o = 32; o; o >>= 1) {
            sq += __shfl_xor(sq, o);
            dt += __shfl_xor(dt, o);
        }
        if (lane == 0) { wsq[a][w] = sq; wdt[a][w] = dt; }
    }
    __syncthreads();

    const float en = fmaxf(sqrtf(weu[0] + weu[1] + weu[2] + weu[3]), 1e-8f);
    float e[8], m = -1e30f;
#pragma unroll
    for (int a = 0; a < 8; ++a) {
        const float sq = wsq[a][0] + wsq[a][1] + wsq[a][2] + wsq[a][3];
        const float dt = wdt[a][0] + wdt[a][1] + wdt[a][2] + wdt[a][3];
        const float hn = fmaxf(sqrtf(sq), 1e-8f);
        e[a] = dt / (hn * en);
        m = fmaxf(m, e[a]);
    }
    float sum = 0.f;
#pragma unroll
    for (int a = 0; a < 8; ++a) { e[a] = expf(e[a] - m); sum += e[a]; }
    const float inv = 1.f / sum;
    float comb = 0.f;
#pragma unroll
    for (int a = 0; a < 8; ++a) comb = fmaf(e[a] * inv, h[a], comb);
    s_out[(long)sb * 256 + tid] = comb;
}

// ---------------------------------------------------------------------------
// K5: MLP layer-1 + W2 partial logits; last block reduces + softmax -> out.
// Grid = 32 b x 16 mb = 512 WGs x 256 thr; each wave does 16 rows.
// ---------------------------------------------------------------------------
__global__ __launch_bounds__(256) void k_mlp_out(
    const float* __restrict__ s_out, const float* __restrict__ W1, const float* __restrict__ b1,
    const float* __restrict__ W2, const float* __restrict__ b2,
    float* __restrict__ lp, int* __restrict__ ctr, float* __restrict__ outp)
{
    const int b = blockIdx.x >> 4;
    const int mb = blockIdx.x & 15;
    const int tid = threadIdx.x;
    const int w = tid >> 6, lane = tid & 63;

    __shared__ float conc[512];
    __shared__ float red[4][3];
    __shared__ int sflag;

    conc[tid] = s_out[(long)b * 256 + tid];
    conc[256 + tid] = s_out[(long)(32 + b) * 256 + tid];
    __syncthreads();

    const float4* conc4 = (const float4*)conc;
    const float4 ca = conc4[lane * 2];
    const float4 cb_ = conc4[lane * 2 + 1];

    float p0 = 0.f, p1 = 0.f, p2 = 0.f;
    for (int rr = 0; rr < 16; ++rr) {
        const int m = mb * 64 + w * 16 + rr;
        const float4* wr = (const float4*)(W1 + (long)m * 512);
        const float4 w0 = wr[lane * 2];
        const float4 w1 = wr[lane * 2 + 1];
        float s = fmaf(ca.x, w0.x, 0.f);
        s = fmaf(ca.y, w0.y, s);
        s = fmaf(ca.z, w0.z, s);
        s = fmaf(ca.w, w0.w, s);
        s = fmaf(cb_.x, w1.x, s);
        s = fmaf(cb_.y, w1.y, s);
        s = fmaf(cb_.z, w1.z, s);
        s = fmaf(cb_.w, w1.w, s);
        for (int o = 32; o; o >>= 1) s += __shfl_xor(s, o);
        const float v = fmaxf(s + b1[m], 0.f);
        p0 = fmaf(v, W2[m], p0);
        p1 = fmaf(v, W2[1024 + m], p1);
        p2 = fmaf(v, W2[2048 + m], p2);
    }
    if (lane == 0) { red[w][0] = p0; red[w][1] = p1; red[w][2] = p2; }
    __syncthreads();
    if (tid == 0) {
        const long o = (long)(b * 16 + mb) * 3;
        lp[o + 0] = red[0][0] + red[1][0] + red[2][0] + red[3][0];
        lp[o + 1] = red[0][1] + red[1][1] + red[2][1] + red[3][1];
        lp[o + 2] = red[0][2] + red[1][2] + red[2][2] + red[3][2];
        __threadfence();
        const int old = atomicAdd(ctr, 1);
        sflag = (old == 511) ? 1 : 0;
    }
    __syncthreads();
    if (sflag) {
        __threadfence();
        if (tid < 32) {
            const volatile float* vlp = lp;
            float l0 = b2[0], l1 = b2[1], l2 = b2[2];
#pragma unroll
            for (int k = 0; k < 16; ++k) {
                const long o = (long)(tid * 16 + k) * 3;
                l0 += vlp[o + 0];
                l1 += vlp[o + 1];
                l2 += vlp[o + 2];
            }
            const float mm = fmaxf(l0, fmaxf(l1, l2));
            const float e0 = expf(l0 - mm), e1 = expf(l1 - mm), e2 = expf(l2 - mm);
            const float inv = 1.f / (e0 + e1 + e2);
            outp[tid * 3 + 0] = e0 * inv;
            outp[tid * 3 + 1] = e1 * inv;
            outp[tid * 3 + 2] = e2 * inv;
        }
    }
}

extern "C" void kernel_launch(void* const* d_in, const int* in_sizes, int n_in,
                              void* d_out, int out_size, void* d_ws, size_t ws_size,
                              hipStream_t stream)
{
    const int* sent1 = (const int*)d_in[0];
    const int* ops1 = (const int*)d_in[1];
    const int* oopl1 = (const int*)d_in[2];
    const int* sent2 = (const int*)d_in[3];
    const int* ops2 = (const int*)d_in[4];
    const int* oopl2 = (const int*)d_in[5];
    const float* glove = (const float*)d_in[6];
    const float* Wm = (const float*)d_in[7];
    const float* Um = (const float*)d_in[8];
    const float* bv = (const float*)d_in[9];
    const float* eu = (const float*)d_in[10];
    const float* unk = (const float*)d_in[11];
    const float* W1 = (const float*)d_in[12];
    const float* b1 = (const float*)d_in[13];
    const float* W2 = (const float*)d_in[14];
    const float* b2 = (const float*)d_in[15];
    float* outp = (float*)d_out;

    float* ws = (float*)d_ws;
    float* p0base = ws + OFF_P0;
    float* hh = ws + OFF_HH;
    float* c_leaf = ws + OFF_CLF;
    float* p1base = ws + OFF_P1;
    float* s_out = ws + OFF_SOUT;
    float* lp = ws + OFF_LP;
    int* ctr = (int*)(ws + OFF_CTR);

    hipLaunchKernelGGL(k_pre0, dim3(384, 5), dim3(128), 0, stream,
                       sent1, ops1, oopl1, sent2, ops2, oopl2, glove, unk, Wm, p0base);
    hipLaunchKernelGGL(k_hh, dim3(256), dim3(256), 0, stream, p0base, bv, hh, c_leaf);
    hipLaunchKernelGGL(k_g2, dim3(320, 4), dim3(128), 0, stream, hh, Um, p1base);
    hipLaunchKernelGGL(k_finish, dim3(64), dim3(256), 0, stream,
                       p1base, bv, c_leaf, eu, s_out, ctr);
    hipLaunchKernelGGL(k_mlp_out, dim3(512), dim3(256), 0, stream,
                       s_out, W1, b1, W2, b2, lp, ctr, outp);
}